// Round 5
// baseline (654.277 us; speedup 1.0000x reference)
//
#include <hip/hip_runtime.h>

// Langevin dynamics, bit-matched to JAX Threefry-2x32 *partitionable* RNG:
//   split(key, n):  keys[t] = threefry2x32(key=(0,1), counter=(0, t))
//   random_bits32:  bits[i] = o0 ^ o1 of threefry2x32(key_t, counter=(0, i))
// Two elements per thread (j, j+H), the two threefry/erfinv chains
// hand-interleaved for guaranteed in-wave ILP. Keys prefetched one step
// ahead into registers. 1024 blocks, __launch_bounds__(256,4) -> 128 VGPR
// budget so both chains + constants stay in registers.

__device__ __forceinline__ void tf2x32(unsigned k0, unsigned k1,
                                       unsigned c0, unsigned c1,
                                       unsigned& o0, unsigned& o1) {
  const unsigned k2 = k0 ^ k1 ^ 0x1BD11BDAu;
  unsigned x0 = c0 + k0, x1 = c1 + k1;
#define TF1(R) x0 += x1; x1 = ((x1 << (R)) | (x1 >> (32 - (R)))); x1 ^= x0;
  TF1(13) TF1(15) TF1(26) TF1(6)  x0 += k1; x1 += k2 + 1u;
  TF1(17) TF1(29) TF1(16) TF1(24) x0 += k2; x1 += k0 + 2u;
  TF1(13) TF1(15) TF1(26) TF1(6)  x0 += k0; x1 += k1 + 3u;
  TF1(17) TF1(29) TF1(16) TF1(24) x0 += k1; x1 += k2 + 4u;
  TF1(13) TF1(15) TF1(26) TF1(6)  x0 += k2; x1 += k0 + 5u;
#undef TF1
  o0 = x0; o1 = x1;
}

// Two interleaved threefry chains sharing one pre-expanded key schedule
// w[0..7] = {k0, k1, k2, k2+1, k0+2, k1+3, k2+4, k0+5}; counters (0, ca/cb).
__device__ __forceinline__ void tf_fold2(const unsigned w[8],
                                         unsigned ca, unsigned cb,
                                         unsigned& ra, unsigned& rb) {
  unsigned a0 = w[0], a1 = ca + w[1];
  unsigned b0 = w[0], b1 = cb + w[1];
#define TFR2(R)                                   \
  a0 += a1; b0 += b1;                             \
  a1 = ((a1 << (R)) | (a1 >> (32 - (R)))) ^ a0;   \
  b1 = ((b1 << (R)) | (b1 >> (32 - (R)))) ^ b0;
#define TFINJ2(i0, i1) a0 += w[i0]; b0 += w[i0]; a1 += w[i1]; b1 += w[i1];
  TFR2(13) TFR2(15) TFR2(26) TFR2(6)  TFINJ2(1, 3)
  TFR2(17) TFR2(29) TFR2(16) TFR2(24) TFINJ2(2, 4)
  TFR2(13) TFR2(15) TFR2(26) TFR2(6)  TFINJ2(0, 5)
  TFR2(17) TFR2(29) TFR2(16) TFR2(24) TFINJ2(1, 6)
  TFR2(13) TFR2(15) TFR2(26) TFR2(6)  TFINJ2(2, 7)
#undef TFR2
#undef TFINJ2
  ra = a0 ^ a1;
  rb = b0 ^ b1;
}

// uniform(-0.99999994, 1) -> sqrt(2)*erfinv(u): XLA ErfInv32 (Giles) poly,
// branchless, two elements interleaved. log1p(-m) via 1-ulp hw log2 path
// (Sterbenz-exact 1-m for m>=0.5; ln2 split HI+LO) — ~2-ulp agreement.
__device__ __forceinline__ void b2n2(unsigned bba, unsigned bbb,
                                     float& na, float& nb) {
  const float fa = __uint_as_float((bba >> 9) | 0x3F800000u) - 1.0f;
  const float fb = __uint_as_float((bbb >> 9) | 0x3F800000u) - 1.0f;
  const float ua = fmaf(fa, 2.0f, -0.99999994f);
  const float ub = fmaf(fb, 2.0f, -0.99999994f);
  const float ma = ua * ua, mb = ub * ub;
  const float la = __log2f(1.0f - ma);
  const float lb = __log2f(1.0f - mb);
  const float wa = fmaf(la, -0.69314718246459961f, la * 1.9046543e-09f);
  const float wb = fmaf(lb, -0.69314718246459961f, lb * 1.9046543e-09f);
  const bool sa = wa < 5.0f, sb = wb < 5.0f;
  const float za = sa ? (wa - 2.5f) : (__builtin_amdgcn_sqrtf(wa) - 3.0f);
  const float zb = sb ? (wb - 2.5f) : (__builtin_amdgcn_sqrtf(wb) - 3.0f);
  float pa =           sa ? 2.81022636e-08f  : -0.000200214257f;
  float pb =           sb ? 2.81022636e-08f  : -0.000200214257f;
  pa = fmaf(pa, za,    sa ? 3.43273939e-07f  :  0.000100950558f);
  pb = fmaf(pb, zb,    sb ? 3.43273939e-07f  :  0.000100950558f);
  pa = fmaf(pa, za,    sa ? -3.5233877e-06f  :  0.00134934322f);
  pb = fmaf(pb, zb,    sb ? -3.5233877e-06f  :  0.00134934322f);
  pa = fmaf(pa, za,    sa ? -4.39150654e-06f : -0.00367342844f);
  pb = fmaf(pb, zb,    sb ? -4.39150654e-06f : -0.00367342844f);
  pa = fmaf(pa, za,    sa ? 0.00021858087f   :  0.00573950773f);
  pb = fmaf(pb, zb,    sb ? 0.00021858087f   :  0.00573950773f);
  pa = fmaf(pa, za,    sa ? -0.00125372503f  : -0.0076224613f);
  pb = fmaf(pb, zb,    sb ? -0.00125372503f  : -0.0076224613f);
  pa = fmaf(pa, za,    sa ? -0.00417768164f  :  0.00943887047f);
  pb = fmaf(pb, zb,    sb ? -0.00417768164f  :  0.00943887047f);
  pa = fmaf(pa, za,    sa ? 0.246640727f     :  1.00167406f);
  pb = fmaf(pb, zb,    sb ? 0.246640727f     :  1.00167406f);
  pa = fmaf(pa, za,    sa ? 1.50140941f      :  2.83297682f);
  pb = fmaf(pb, zb,    sb ? 1.50140941f      :  2.83297682f);
  na = __uint_as_float(0x3FB504F3u) * (pa * ua);  // f32(sqrt(2)) * erfinv
  nb = __uint_as_float(0x3FB504F3u) * (pb * ub);
}

__global__ __launch_bounds__(256, 4) void langevin_tf(
    const float* __restrict__ x0p, const float* __restrict__ bias,
    const int* __restrict__ nsteps_p, float* __restrict__ out,
    int H, int ndim) {
  // Pre-expanded key schedule: 8 words/step (+1 step pad for the prefetch).
  __shared__ __align__(16) unsigned skeys[513 * 8];
  const int n_steps = __builtin_amdgcn_readfirstlane(nsteps_p[0]);
  const int nfill = n_steps < 512 ? n_steps : 512;
  for (int l = (int)threadIdx.x; l < nfill; l += (int)blockDim.x) {
    unsigned o0, o1;
    tf2x32(0u, 1u, 0u, (unsigned)l, o0, o1);
    const unsigned k2 = o0 ^ o1 ^ 0x1BD11BDAu;
    unsigned* wp = &skeys[8 * l];
    wp[0] = o0;       wp[1] = o1;       wp[2] = k2;       wp[3] = k2 + 1u;
    wp[4] = o0 + 2u;  wp[5] = o1 + 3u;  wp[6] = k2 + 4u;  wp[7] = o0 + 5u;
  }
  __syncthreads();

  const int j = (int)(blockIdx.x * blockDim.x + threadIdx.x);
  if (j >= H) return;
  const unsigned ca = (unsigned)j;
  const unsigned cb = (unsigned)(j + H);
  float xa = x0p[j];
  float xb = x0p[j + H];
  const float ba = bias[j % ndim];
  const float bb = bias[(j + H) % ndim];

  if (n_steps <= 512) {
    const uint4* sk4 = (const uint4*)skeys;
    uint4 klo = sk4[0], khi = sk4[1];
#pragma unroll 1
    for (int t = 0; t < n_steps; ++t) {
      const uint4 nlo = sk4[2 * t + 2];  // prefetch next step's schedule
      const uint4 nhi = sk4[2 * t + 3];
      const unsigned w[8] = {klo.x, klo.y, klo.z, klo.w,
                             khi.x, khi.y, khi.z, khi.w};
      unsigned ra, rb;
      tf_fold2(w, ca, cb, ra, rb);
      float na, nb;
      b2n2(ra, rb, na, nb);
      // grad = 2*J2*x + 4*J4*x^3 + b = -2x + ((2x)*x)*x + b (ref assoc order)
      const float ga = -2.0f * xa + ((2.0f * xa) * xa) * xa + ba;
      const float gb = -2.0f * xb + ((2.0f * xb) * xb) * xb + bb;
      xa = (xa - ga * 0.01f) + na * 0.1f;
      xb = (xb - gb * 0.01f) + nb * 0.1f;
      klo = nlo; khi = nhi;
    }
  } else {
    // Fallback for n_steps > 512: recompute step key inline.
    for (int t = 0; t < n_steps; ++t) {
      unsigned o0, o1;
      tf2x32(0u, 1u, 0u, (unsigned)t, o0, o1);
      const unsigned k2 = o0 ^ o1 ^ 0x1BD11BDAu;
      const unsigned w[8] = {o0, o1, k2, k2 + 1u, o0 + 2u, o1 + 3u,
                             k2 + 4u, o0 + 5u};
      unsigned ra, rb;
      tf_fold2(w, ca, cb, ra, rb);
      float na, nb;
      b2n2(ra, rb, na, nb);
      const float ga = -2.0f * xa + ((2.0f * xa) * xa) * xa + ba;
      const float gb = -2.0f * xb + ((2.0f * xb) * xb) * xb + bb;
      xa = (xa - ga * 0.01f) + na * 0.1f;
      xb = (xb - gb * 0.01f) + nb * 0.1f;
    }
  }
  out[j] = xa;
  out[j + H] = xb;
}

extern "C" void kernel_launch(void* const* d_in, const int* in_sizes, int n_in,
                              void* d_out, int out_size, void* d_ws, size_t ws_size,
                              hipStream_t stream) {
  (void)n_in; (void)d_ws; (void)ws_size; (void)out_size;
  const float* x0 = (const float*)d_in[0];
  const float* b = (const float*)d_in[1];
  const int* ns = (const int*)d_in[2];
  float* out = (float*)d_out;

  const int n = in_sizes[0];     // 2048*256 = 524288
  const int ndim = in_sizes[1];  // 256
  const int H = n / 2;           // one thread per element pair (j, j+H)
  const int block = 256;
  const int grid = (H + block - 1) / block;  // 1024 blocks -> 4/CU
  hipLaunchKernelGGL(langevin_tf, dim3(grid), dim3(block), 0, stream,
                     x0, b, ns, out, H, ndim);
}

// Round 6
// 593.108 us; speedup vs baseline: 1.1031x; 1.1031x over previous
//
#include <hip/hip_runtime.h>

// Langevin dynamics, bit-matched to JAX Threefry-2x32 *partitionable* RNG:
//   split(key, n):  keys[t] = threefry2x32(key=(0,1), counter=(0, t))
//   random_bits32:  bits[i] = o0 ^ o1 of threefry2x32(key_t, counter=(0, i))
// One element per thread (2048 blocks -> 8 blocks/CU, full occupancy) AND
// two consecutive time-steps per loop iteration with their threefry/erfinv
// chains statement-interleaved (steps t, t+1 noise is independent; only the
// 7-op x-update is serial). R4 tried this via separate calls (compiler
// serialized, VGPR 24); R5 proved the fused interleave form keeps both
// chains live. This composes R3's occupancy with R5's per-wave ILP.

__device__ __forceinline__ void tf2x32(unsigned k0, unsigned k1,
                                       unsigned c0, unsigned c1,
                                       unsigned& o0, unsigned& o1) {
  const unsigned k2 = k0 ^ k1 ^ 0x1BD11BDAu;
  unsigned x0 = c0 + k0, x1 = c1 + k1;
#define TF1(R) x0 += x1; x1 = ((x1 << (R)) | (x1 >> (32 - (R)))); x1 ^= x0;
  TF1(13) TF1(15) TF1(26) TF1(6)  x0 += k1; x1 += k2 + 1u;
  TF1(17) TF1(29) TF1(16) TF1(24) x0 += k2; x1 += k0 + 2u;
  TF1(13) TF1(15) TF1(26) TF1(6)  x0 += k0; x1 += k1 + 3u;
  TF1(17) TF1(29) TF1(16) TF1(24) x0 += k1; x1 += k2 + 4u;
  TF1(13) TF1(15) TF1(26) TF1(6)  x0 += k2; x1 += k0 + 5u;
#undef TF1
  o0 = x0; o1 = x1;
}

// Two interleaved threefry chains with DIFFERENT key schedules (steps t and
// t+1), same counter (0, cj). Schedule w[0..7] = {k0,k1,k2,k2+1,k0+2,k1+3,
// k2+4,k0+5}. Statement-interleaved so both chains stay live.
__device__ __forceinline__ void tf_fold2k(const unsigned wa[8],
                                          const unsigned wb[8], unsigned cj,
                                          unsigned& ra, unsigned& rb) {
  unsigned a0 = wa[0], a1 = cj + wa[1];
  unsigned b0 = wb[0], b1 = cj + wb[1];
#define TFR2(R)                                   \
  a0 += a1; b0 += b1;                             \
  a1 = ((a1 << (R)) | (a1 >> (32 - (R)))) ^ a0;   \
  b1 = ((b1 << (R)) | (b1 >> (32 - (R)))) ^ b0;
#define TFINJ2(i0, i1) a0 += wa[i0]; b0 += wb[i0]; a1 += wa[i1]; b1 += wb[i1];
  TFR2(13) TFR2(15) TFR2(26) TFR2(6)  TFINJ2(1, 3)
  TFR2(17) TFR2(29) TFR2(16) TFR2(24) TFINJ2(2, 4)
  TFR2(13) TFR2(15) TFR2(26) TFR2(6)  TFINJ2(0, 5)
  TFR2(17) TFR2(29) TFR2(16) TFR2(24) TFINJ2(1, 6)
  TFR2(13) TFR2(15) TFR2(26) TFR2(6)  TFINJ2(2, 7)
#undef TFR2
#undef TFINJ2
  ra = a0 ^ a1;
  rb = b0 ^ b1;
}

// uniform(-0.99999994, 1) -> sqrt(2)*erfinv(u): XLA ErfInv32 (Giles) poly,
// branchless, two steps interleaved. log1p(-m) via hw log2 (Sterbenz-exact
// 1-m for m>=0.5) * ln2 — ~2-ulp agreement with XLA, damped by dynamics.
__device__ __forceinline__ void b2n2(unsigned bba, unsigned bbb,
                                     float& na, float& nb) {
  const float fa = __uint_as_float((bba >> 9) | 0x3F800000u) - 1.0f;
  const float fb = __uint_as_float((bbb >> 9) | 0x3F800000u) - 1.0f;
  const float ua = fmaf(fa, 2.0f, -0.99999994f);
  const float ub = fmaf(fb, 2.0f, -0.99999994f);
  const float ma = ua * ua, mb = ub * ub;
  const float la = __log2f(1.0f - ma);
  const float lb = __log2f(1.0f - mb);
  const float wa = la * -0.693147180559945f;   // -log1p(-m), ~2 ulp
  const float wb = lb * -0.693147180559945f;
  const bool sa = wa < 5.0f, sb = wb < 5.0f;
  const float za = sa ? (wa - 2.5f) : (__builtin_amdgcn_sqrtf(wa) - 3.0f);
  const float zb = sb ? (wb - 2.5f) : (__builtin_amdgcn_sqrtf(wb) - 3.0f);
  float pa =           sa ? 2.81022636e-08f  : -0.000200214257f;
  float pb =           sb ? 2.81022636e-08f  : -0.000200214257f;
  pa = fmaf(pa, za,    sa ? 3.43273939e-07f  :  0.000100950558f);
  pb = fmaf(pb, zb,    sb ? 3.43273939e-07f  :  0.000100950558f);
  pa = fmaf(pa, za,    sa ? -3.5233877e-06f  :  0.00134934322f);
  pb = fmaf(pb, zb,    sb ? -3.5233877e-06f  :  0.00134934322f);
  pa = fmaf(pa, za,    sa ? -4.39150654e-06f : -0.00367342844f);
  pb = fmaf(pb, zb,    sb ? -4.39150654e-06f : -0.00367342844f);
  pa = fmaf(pa, za,    sa ? 0.00021858087f   :  0.00573950773f);
  pb = fmaf(pb, zb,    sb ? 0.00021858087f   :  0.00573950773f);
  pa = fmaf(pa, za,    sa ? -0.00125372503f  : -0.0076224613f);
  pb = fmaf(pb, zb,    sb ? -0.00125372503f  : -0.0076224613f);
  pa = fmaf(pa, za,    sa ? -0.00417768164f  :  0.00943887047f);
  pb = fmaf(pb, zb,    sb ? -0.00417768164f  :  0.00943887047f);
  pa = fmaf(pa, za,    sa ? 0.246640727f     :  1.00167406f);
  pb = fmaf(pb, zb,    sb ? 0.246640727f     :  1.00167406f);
  pa = fmaf(pa, za,    sa ? 1.50140941f      :  2.83297682f);
  pb = fmaf(pb, zb,    sb ? 1.50140941f      :  2.83297682f);
  na = __uint_as_float(0x3FB504F3u) * (pa * ua);  // f32(sqrt(2)) * erfinv
  nb = __uint_as_float(0x3FB504F3u) * (pb * ub);
}

__global__ __launch_bounds__(256, 8) void langevin_tf(
    const float* __restrict__ x0p, const float* __restrict__ bias,
    const int* __restrict__ nsteps_p, float* __restrict__ out,
    int N, int ndim) {
  // Pre-expanded key schedule: 8 words/step, 16 KB for 512 steps.
  __shared__ __align__(16) unsigned skeys[512 * 8];
  const int n_steps = __builtin_amdgcn_readfirstlane(nsteps_p[0]);
  const int nfill = n_steps < 512 ? n_steps : 512;
  for (int l = (int)threadIdx.x; l < nfill; l += (int)blockDim.x) {
    unsigned o0, o1;
    tf2x32(0u, 1u, 0u, (unsigned)l, o0, o1);
    const unsigned k2 = o0 ^ o1 ^ 0x1BD11BDAu;
    unsigned* wp = &skeys[8 * l];
    wp[0] = o0;       wp[1] = o1;       wp[2] = k2;       wp[3] = k2 + 1u;
    wp[4] = o0 + 2u;  wp[5] = o1 + 3u;  wp[6] = k2 + 4u;  wp[7] = o0 + 5u;
  }
  __syncthreads();

  const int j = (int)(blockIdx.x * blockDim.x + threadIdx.x);
  if (j >= N) return;
  const unsigned cj = (unsigned)j;
  float x = x0p[j];
  const float b = bias[j % ndim];

  if (n_steps <= 512) {
    const uint4* sk4 = (const uint4*)skeys;
    int t = 0;
#pragma unroll 1
    for (; t + 1 < n_steps; t += 2) {
      const uint4 a_lo = sk4[2 * t + 0], a_hi = sk4[2 * t + 1];  // step t
      const uint4 b_lo = sk4[2 * t + 2], b_hi = sk4[2 * t + 3];  // step t+1
      const unsigned wa[8] = {a_lo.x, a_lo.y, a_lo.z, a_lo.w,
                              a_hi.x, a_hi.y, a_hi.z, a_hi.w};
      const unsigned wb[8] = {b_lo.x, b_lo.y, b_lo.z, b_lo.w,
                              b_hi.x, b_hi.y, b_hi.z, b_hi.w};
      unsigned ra, rb;
      tf_fold2k(wa, wb, cj, ra, rb);   // steps t, t+1: independent chains
      float na, nb;
      b2n2(ra, rb, na, nb);
      // grad = 2*J2*x + 4*J4*x^3 + b = -2x + ((2x)*x)*x + b (ref assoc order)
      float g = -2.0f * x + ((2.0f * x) * x) * x + b;
      x = (x - g * 0.01f) + na * 0.1f;
      g = -2.0f * x + ((2.0f * x) * x) * x + b;
      x = (x - g * 0.01f) + nb * 0.1f;
    }
    if (t < n_steps) {  // odd-step tail
      const uint4 a_lo = sk4[2 * t + 0], a_hi = sk4[2 * t + 1];
      const unsigned wa[8] = {a_lo.x, a_lo.y, a_lo.z, a_lo.w,
                              a_hi.x, a_hi.y, a_hi.z, a_hi.w};
      unsigned ra, rb;
      tf_fold2k(wa, wa, cj, ra, rb);   // rb unused
      float na, nb;
      b2n2(ra, ra, na, nb);
      const float g = -2.0f * x + ((2.0f * x) * x) * x + b;
      x = (x - g * 0.01f) + na * 0.1f;
    }
  } else {
    // Fallback for n_steps > 512: recompute step keys inline, 2 steps/iter.
    for (int t = 0; t < n_steps; t += 2) {
      unsigned oa0, oa1, ob0, ob1;
      tf2x32(0u, 1u, 0u, (unsigned)t, oa0, oa1);
      tf2x32(0u, 1u, 0u, (unsigned)(t + 1), ob0, ob1);
      const unsigned ka2 = oa0 ^ oa1 ^ 0x1BD11BDAu;
      const unsigned kb2 = ob0 ^ ob1 ^ 0x1BD11BDAu;
      const unsigned wa[8] = {oa0, oa1, ka2, ka2 + 1u, oa0 + 2u, oa1 + 3u,
                              ka2 + 4u, oa0 + 5u};
      const unsigned wb[8] = {ob0, ob1, kb2, kb2 + 1u, ob0 + 2u, ob1 + 3u,
                              kb2 + 4u, ob0 + 5u};
      unsigned ra, rb;
      tf_fold2k(wa, wb, cj, ra, rb);
      float na, nb;
      b2n2(ra, rb, na, nb);
      float g = -2.0f * x + ((2.0f * x) * x) * x + b;
      x = (x - g * 0.01f) + na * 0.1f;
      if (t + 1 < n_steps) {
        g = -2.0f * x + ((2.0f * x) * x) * x + b;
        x = (x - g * 0.01f) + nb * 0.1f;
      }
    }
  }
  out[j] = x;
}

extern "C" void kernel_launch(void* const* d_in, const int* in_sizes, int n_in,
                              void* d_out, int out_size, void* d_ws, size_t ws_size,
                              hipStream_t stream) {
  (void)n_in; (void)d_ws; (void)ws_size; (void)out_size;
  const float* x0 = (const float*)d_in[0];
  const float* b = (const float*)d_in[1];
  const int* ns = (const int*)d_in[2];
  float* out = (float*)d_out;

  const int n = in_sizes[0];     // 2048*256 = 524288
  const int ndim = in_sizes[1];  // 256
  const int block = 256;
  const int grid = (n + block - 1) / block;  // 2048 blocks -> 8/CU, 32 waves/CU
  hipLaunchKernelGGL(langevin_tf, dim3(grid), dim3(block), 0, stream,
                     x0, b, ns, out, n, ndim);
}